// Round 14
// baseline (315.170 us; speedup 1.0000x reference)
//
#include <hip/hip_runtime.h>

#define B_  128
#define LC_ 512
#define LM_ 512
#define D_  512

typedef __attribute__((ext_vector_type(8))) short short8;
typedef __attribute__((ext_vector_type(16))) float f32x16;
typedef unsigned int u32;

__device__ __forceinline__ unsigned short bf16_rn(float x) {
  unsigned u = __float_as_uint(x);
  unsigned r = u + 0x7fffu + ((u >> 16) & 1u);
  return (unsigned short)(r >> 16);
}

__device__ __forceinline__ void gl_lds16(const void* g, void* l) {
  __builtin_amdgcn_global_load_lds((const __attribute__((address_space(1))) u32*)g,
                                   (__attribute__((address_space(3))) u32*)l, 16, 0, 0);
}

// one fp32 -> (hi,lo) bf16 split + u-dot accumulate; constant IDX only
#define CVT1(SRC, WS, AH, AL, IDX, ACCU)                         \
  { unsigned short hb_ = bf16_rn(SRC);                           \
    float hf_ = __uint_as_float((u32)hb_ << 16);                 \
    AH[IDX] = (short)hb_;                                        \
    AL[IDX] = (short)bf16_rn((SRC) - hf_);                       \
    ACCU = fmaf((SRC), (WS), ACCU); }

// ---------------- k_cvt_main: main fp32 -> tiled fragment-order bf16 planes
// Bt[b][ks][mt][lane][8]; also fused v = main·W. Wave = one (b, mt) tile.
__global__ __launch_bounds__(256) void k_cvt_main(
    const float* __restrict__ mn, const float* __restrict__ W,
    short* __restrict__ BtH, short* __restrict__ BtL,
    float* __restrict__ v) {
  __shared__ float sW[512];
  int tid = threadIdx.x;
  sW[tid] = W[tid];
  sW[tid + 256] = W[tid + 256];
  __syncthreads();
  int wave = blockIdx.x * 4 + (tid >> 6);
  int b = wave >> 4, mt = wave & 15;
  int lane = tid & 63, rowl = lane & 31, h = lane >> 5;
  const float* src = mn + ((size_t)b * LM_ + 32 * mt + rowl) * D_ + 8 * h;
  float acc = 0.f;
  for (int ks = 0; ks < 32; ks++) {
    float4 f0 = *(const float4*)(src + 16 * ks);
    float4 f1 = *(const float4*)(src + 16 * ks + 4);
    int k = 16 * ks + 8 * h;
    float4 w0 = *(const float4*)&sW[k];
    float4 w1 = *(const float4*)&sW[k + 4];
    short8 vh, vl;
    CVT1(f0.x, w0.x, vh, vl, 0, acc); CVT1(f0.y, w0.y, vh, vl, 1, acc);
    CVT1(f0.z, w0.z, vh, vl, 2, acc); CVT1(f0.w, w0.w, vh, vl, 3, acc);
    CVT1(f1.x, w1.x, vh, vl, 4, acc); CVT1(f1.y, w1.y, vh, vl, 5, acc);
    CVT1(f1.z, w1.z, vh, vl, 6, acc); CVT1(f1.w, w1.w, vh, vl, 7, acc);
    size_t off = (((size_t)b * 32 + ks) * 16 + mt) * 512 + (size_t)lane * 8;
    *(short8*)(BtH + off) = vh;
    *(short8*)(BtL + off) = vl;
  }
  acc += __shfl_xor(acc, 32, 64);
  if (h == 0) v[b * LM_ + 32 * mt + rowl] = acc;
}

// ---------------- k_scores_mfma8: 128c x 512m, 8 waves, barrier-free K-loop
// with WAVE-PRIVATE double-buffered gl_lds pipeline for B: each wave stages
// its own next-ks fragments into its private LDS region (no cross-wave dep,
// no barriers), fenced by one conservative vmcnt(0) per iteration placed
// where the prefetch has had a full MFMA block (~810 cy) to land. Takes the
// ~600-cy L3 B-load latency off the MFMA dependency chain (R13 diagnosis).
struct __align__(16) Smem8 {
  short8 Bpipe[8][2][8][64];   // [wv][buf][frag=mtl*2+pl][lane]  128 KB
  float sW[512];               // 2 KB
  float red[4][128];           // 2 KB
  float cmb[128];
  float uld[128];
  float tpw[2][4][128];        // 4 KB
};

__global__ __launch_bounds__(512, 1) void k_scores_mfma8(
    const float* __restrict__ ctx, const short* __restrict__ BtH,
    const short* __restrict__ BtL, const float* __restrict__ W,
    float* __restrict__ P, float* __restrict__ tpart) {
  __shared__ Smem8 sm;
  int p = blockIdx.x;
  int b = (p & 7) | ((p >> 5) << 3);   // 4 c-blocks of a batch -> same XCD
  int cblk = (p >> 3) & 3;
  int c0 = cblk * 128;
  int tid = threadIdx.x;
  int lane = tid & 63, wv = tid >> 6;
  int rowl = lane & 31, h = lane >> 5;
  int rt0 = (wv >> 2) * 2;             // waves 0-3: rows 0-63; 4-7: 64-127

  f32x16 acc0[4], acc1[4];             // 128 acc regs
  #pragma unroll
  for (int m = 0; m < 4; m++)
    #pragma unroll
    for (int j = 0; j < 16; j++) { acc0[m][j] = 0.f; acc1[m][j] = 0.f; }

  const float* ar0 = ctx + ((size_t)b * LC_ + c0 + 32 * rt0 + rowl) * D_ + 8 * h;
  const float* ar1 = ar0 + 32 * D_;
  // per-lane global base for this wave's 4 B column-tiles
  size_t boff0 = (((size_t)b * 32) * 16 + (wv & 3) * 4) * 512 + (size_t)lane * 8;

  // stage B fragments for slice ks into private buffer bf
  auto stageB = [&](int bf, int ks) {
    size_t bo = boff0 + (size_t)ks * (16 * 512);
    #pragma unroll
    for (int mtl = 0; mtl < 4; mtl++) {
      gl_lds16(BtH + bo + (size_t)mtl * 512, &sm.Bpipe[wv][bf][mtl * 2][0]);
      gl_lds16(BtL + bo + (size_t)mtl * 512, &sm.Bpipe[wv][bf][mtl * 2 + 1][0]);
    }
  };

  sm.sW[tid] = W[tid];
  if (tid < 128) sm.uld[tid] = 0.f;
  stageB(0, 0);
  float accu0 = 0.f, accu1 = 0.f;
  __syncthreads();                     // sW visible (also drains prologue)

  for (int ks = 0; ks < 32; ks++) {
    int buf = ks & 1;
    // fence: the gl_lds that filled buf (issued last iteration, a full MFMA
    // block ago) must be complete before we ds_read it. Conservative drain.
    asm volatile("s_waitcnt vmcnt(0)" ::: "memory");
    short8 bh[4], bl[4];
    #pragma unroll
    for (int mtl = 0; mtl < 4; mtl++) {
      bh[mtl] = sm.Bpipe[wv][buf][mtl * 2][lane];
      bl[mtl] = sm.Bpipe[wv][buf][mtl * 2 + 1][lane];
    }
    if (ks < 31) stageB(buf ^ 1, ks + 1);   // prefetch next slice (async)

    // ---- A: load fp32 + in-register hi/lo cvt (+ u-dot) ----
    int k = 16 * ks + 8 * h;
    float4 w0 = *(const float4*)&sm.sW[k];
    float4 w1 = *(const float4*)&sm.sW[k + 4];
    short8 ah0, al0, ah1, al1;
    {
      const float* p0 = ar0 + 16 * ks;
      float4 g0 = *(const float4*)p0;
      float4 g1 = *(const float4*)(p0 + 4);
      CVT1(g0.x, w0.x, ah0, al0, 0, accu0); CVT1(g0.y, w0.y, ah0, al0, 1, accu0);
      CVT1(g0.z, w0.z, ah0, al0, 2, accu0); CVT1(g0.w, w0.w, ah0, al0, 3, accu0);
      CVT1(g1.x, w1.x, ah0, al0, 4, accu0); CVT1(g1.y, w1.y, ah0, al0, 5, accu0);
      CVT1(g1.z, w1.z, ah0, al0, 6, accu0); CVT1(g1.w, w1.w, ah0, al0, 7, accu0);
    }
    {
      const float* p1 = ar1 + 16 * ks;
      float4 g0 = *(const float4*)p1;
      float4 g1 = *(const float4*)(p1 + 4);
      CVT1(g0.x, w0.x, ah1, al1, 0, accu1); CVT1(g0.y, w0.y, ah1, al1, 1, accu1);
      CVT1(g0.z, w0.z, ah1, al1, 2, accu1); CVT1(g0.w, w0.w, ah1, al1, 3, accu1);
      CVT1(g1.x, w1.x, ah1, al1, 4, accu1); CVT1(g1.y, w1.y, ah1, al1, 5, accu1);
      CVT1(g1.z, w1.z, ah1, al1, 6, accu1); CVT1(g1.w, w1.w, ah1, al1, 7, accu1);
    }
    // ---- MFMA (3-term split, same order as R5-R13) ----
    #pragma unroll
    for (int mtl = 0; mtl < 4; mtl++) {
      acc0[mtl] = __builtin_amdgcn_mfma_f32_32x32x16_bf16(ah0, bh[mtl], acc0[mtl], 0, 0, 0);
      acc0[mtl] = __builtin_amdgcn_mfma_f32_32x32x16_bf16(ah0, bl[mtl], acc0[mtl], 0, 0, 0);
      acc0[mtl] = __builtin_amdgcn_mfma_f32_32x32x16_bf16(al0, bh[mtl], acc0[mtl], 0, 0, 0);
      acc1[mtl] = __builtin_amdgcn_mfma_f32_32x32x16_bf16(ah1, bh[mtl], acc1[mtl], 0, 0, 0);
      acc1[mtl] = __builtin_amdgcn_mfma_f32_32x32x16_bf16(ah1, bl[mtl], acc1[mtl], 0, 0, 0);
      acc1[mtl] = __builtin_amdgcn_mfma_f32_32x32x16_bf16(al1, bh[mtl], acc1[mtl], 0, 0, 0);
    }
  }

  // u for this block's 128 c-rows (waves 0 and 4 hold distinct row ranges)
  accu0 += __shfl_xor(accu0, 32, 64);
  accu1 += __shfl_xor(accu1, 32, 64);
  if ((wv & 3) == 0 && h == 0) {
    sm.uld[64 * (wv >> 2) + rowl] = accu0;
    sm.uld[64 * (wv >> 2) + 32 + rowl] = accu1;
  }

  // ---- softmax over m=512 per c-row (cross-wave via LDS) ----
  #pragma unroll
  for (int r = 0; r < 2; r++)
    #pragma unroll
    for (int j = 0; j < 16; j++) {
      float a0 = r ? acc1[0][j] : acc0[0][j];
      float a1 = r ? acc1[1][j] : acc0[1][j];
      float a2 = r ? acc1[2][j] : acc0[2][j];
      float a3 = r ? acc1[3][j] : acc0[3][j];
      float mx = fmaxf(fmaxf(a0, a1), fmaxf(a2, a3));
      #pragma unroll
      for (int s = 1; s <= 16; s <<= 1) mx = fmaxf(mx, __shfl_xor(mx, s, 64));
      if (rowl == 0)
        sm.red[wv & 3][64 * (wv >> 2) + 32 * r + (j & 3) + 8 * (j >> 2) + 4 * h] = mx;
    }
  __syncthreads();
  if (tid < 128)
    sm.cmb[tid] = fmaxf(fmaxf(sm.red[0][tid], sm.red[1][tid]),
                        fmaxf(sm.red[2][tid], sm.red[3][tid]));
  __syncthreads();
  #pragma unroll
  for (int r = 0; r < 2; r++)
    #pragma unroll
    for (int j = 0; j < 16; j++) {
      int row = 64 * (wv >> 2) + 32 * r + (j & 3) + 8 * (j >> 2) + 4 * h;
      float mx = sm.cmb[row];
      float s = 0.f;
      #pragma unroll
      for (int mtl = 0; mtl < 4; mtl++) {
        float e = __expf((r ? acc1[mtl][j] : acc0[mtl][j]) - mx);
        if (r) acc1[mtl][j] = e; else acc0[mtl][j] = e;
        s += e;
      }
      #pragma unroll
      for (int st = 1; st <= 16; st <<= 1) s += __shfl_xor(s, st, 64);
      if (rowl == 0) sm.red[wv & 3][row] = s;
    }
  __syncthreads();
  if (tid < 128)
    sm.cmb[tid] = sm.red[0][tid] + sm.red[1][tid] + sm.red[2][tid] + sm.red[3][tid];
  __syncthreads();

  // ---- P write + fused t-partials (wave owns cols [128(wv&3), +128)) ----
  float* Pb = P + ((size_t)b * LC_ + c0) * LM_;
  float tp[4] = {0.f, 0.f, 0.f, 0.f};
  #pragma unroll
  for (int r = 0; r < 2; r++)
    #pragma unroll
    for (int j = 0; j < 16; j++) {
      int row = 64 * (wv >> 2) + 32 * r + (j & 3) + 8 * (j >> 2) + 4 * h;
      float rinv = 1.f / sm.cmb[row];
      float uu = sm.uld[row];
      #pragma unroll
      for (int mtl = 0; mtl < 4; mtl++) {
        float pv = (r ? acc1[mtl][j] : acc0[mtl][j]) * rinv;
        Pb[(size_t)row * LM_ + 128 * (wv & 3) + 32 * mtl + rowl] = pv;
        tp[mtl] = fmaf(pv, uu, tp[mtl]);
      }
    }
  #pragma unroll
  for (int mtl = 0; mtl < 4; mtl++) tp[mtl] += __shfl_xor(tp[mtl], 32, 64);
  if (h == 0) {
    #pragma unroll
    for (int mtl = 0; mtl < 4; mtl++)
      sm.tpw[wv >> 2][wv & 3][32 * mtl + rowl] = tp[mtl];
  }
  __syncthreads();
  {
    int m = tid;
    tpart[((size_t)b * 4 + cblk) * LM_ + m] =
        sm.tpw[0][m >> 7][m & 127] + sm.tpw[1][m >> 7][m & 127];
  }
}

// ---------------- k_tw: t = v - sum(tpart, 4); w = softmax(t) --------------
__global__ __launch_bounds__(256) void k_tw(const float* __restrict__ tpart,
                                            const float* __restrict__ v,
                                            float* __restrict__ w_) {
  int b = blockIdx.x;
  int tid = threadIdx.x;
  int m0 = tid * 2;
  const float* tp = tpart + (size_t)b * 4 * LM_;
  float s0 = 0.f, s1 = 0.f;
  #pragma unroll
  for (int cb = 0; cb < 4; cb++) {
    s0 += tp[cb * LM_ + m0];
    s1 += tp[cb * LM_ + m0 + 1];
  }
  float x0 = v[b * LM_ + m0] - s0;
  float x1 = v[b * LM_ + m0 + 1] - s1;
  float mx = fmaxf(x0, x1);
  #pragma unroll
  for (int s = 32; s >= 1; s >>= 1) mx = fmaxf(mx, __shfl_xor(mx, s, 64));
  __shared__ float redm[4], reds[4];
  int wvv = tid >> 6, ln = tid & 63;
  if (ln == 0) redm[wvv] = mx;
  __syncthreads();
  mx = fmaxf(fmaxf(redm[0], redm[1]), fmaxf(redm[2], redm[3]));
  float e0 = __expf(x0 - mx), e1 = __expf(x1 - mx);
  float sum = e0 + e1;
  #pragma unroll
  for (int s = 32; s >= 1; s >>= 1) sum += __shfl_xor(sum, s, 64);
  if (ln == 0) reds[wvv] = sum;
  __syncthreads();
  sum = reds[0] + reds[1] + reds[2] + reds[3];
  float rinv = 1.0f / sum;
  float2 o; o.x = e0 * rinv; o.y = e1 * rinv;
  *(float2*)&w_[b * LM_ + m0] = o;
}

// ---------------- k_q: q[b,c] = sum_m P[b,c,m]*w[b,m] ----------------------
__global__ __launch_bounds__(256) void k_q(const float* __restrict__ P,
                                           const float* __restrict__ w,
                                           float* __restrict__ q) {
  int b = blockIdx.y;
  int c0 = blockIdx.x * 32;
  int wvv = threadIdx.x >> 6, ln = threadIdx.x & 63;
  __shared__ float sw[LM_];
  *(float2*)&sw[threadIdx.x * 2] = *(const float2*)&w[b * LM_ + threadIdx.x * 2];
  __syncthreads();
  #pragma unroll
  for (int rr = 0; rr < 8; rr++) {
    int c = c0 + wvv * 8 + rr;
    const float4* Pr = (const float4*)(P + ((size_t)b * LC_ + c) * LM_) + ln * 2;
    float4 p0 = Pr[0], p1 = Pr[1];
    const float4* wr = (const float4*)sw + ln * 2;
    float4 w0 = wr[0], w1 = wr[1];
    float acc = p0.x*w0.x + p0.y*w0.y + p0.z*w0.z + p0.w*w0.w
              + p1.x*w1.x + p1.y*w1.y + p1.z*w1.z + p1.w*w1.w;
    #pragma unroll
    for (int s = 32; s >= 1; s >>= 1) acc += __shfl_xor(acc, s, 64);
    if (ln == 0) q[b * LC_ + c] = acc;
  }
}

// ---------------- k_out: out[b,d] = sum_m w*main - sum_c q*ctx -------------
__global__ __launch_bounds__(256) void k_out(const float* __restrict__ ctx,
                                             const float* __restrict__ mn,
                                             const float* __restrict__ w,
                                             const float* __restrict__ q,
                                             float* __restrict__ out) {
  int b = blockIdx.y;
  int d0 = blockIdx.x * 64;
  int td = threadIdx.x & 63;
  int tg = threadIdx.x >> 6;
  const float* Mb = mn  + (size_t)b * LM_ * D_ + d0;
  const float* Cb = ctx + (size_t)b * LC_ * D_ + d0;
  const float* wb = w + b * LM_;
  const float* qb = q + b * LC_;
  float acc = 0.f;
  #pragma unroll 4
  for (int m = tg; m < LM_; m += 4) acc += wb[m] * Mb[(size_t)m * D_ + td];
  #pragma unroll 4
  for (int c = tg; c < LC_; c += 4) acc -= qb[c] * Cb[(size_t)c * D_ + td];
  __shared__ float red[4][64];
  red[tg][td] = acc;
  __syncthreads();
  if (tg == 0)
    out[b * D_ + d0 + td] = red[0][td] + red[1][td] + red[2][td] + red[3][td];
}

// =====================  LAUNCH  ============================================
extern "C" void kernel_launch(void* const* d_in, const int* in_sizes, int n_in,
                              void* d_out, int out_size, void* d_ws, size_t ws_size,
                              hipStream_t stream) {
  const float* ctx = (const float*)d_in[0];
  const float* mn  = (const float*)d_in[1];
  const float* W   = (const float*)d_in[2];
  float* out = (float*)d_out;

  char* base = (char*)d_ws;
  size_t nPbytes = (size_t)B_ * LC_ * LM_ * 4;       // 134 MB
  size_t planeB  = (size_t)B_ * LM_ * D_ * 2;        // 67 MB per plane

  float* P   = (float*)base;
  short* BtH = (short*)(base + nPbytes);
  short* BtL = (short*)(base + nPbytes + planeB);
  char* p2 = base + nPbytes + 2 * planeB;
  float* tpart = (float*)p2;  p2 += (size_t)B_ * 4 * LM_ * 4;
  float* v = (float*)p2;      p2 += (size_t)B_ * LM_ * 4;
  float* w = (float*)p2;      p2 += (size_t)B_ * LM_ * 4;
  float* q = (float*)p2;

  k_cvt_main<<<dim3(512), 256, 0, stream>>>(mn, W, BtH, BtL, v);
  k_scores_mfma8<<<dim3(512), 512, 0, stream>>>(ctx, BtH, BtL, W, P, tpart);
  k_tw<<<dim3(B_), 256, 0, stream>>>(tpart, v, w);
  k_q<<<dim3(LC_ / 32, B_), 256, 0, stream>>>(P, w, q);
  k_out<<<dim3(D_ / 64, B_), 256, 0, stream>>>(ctx, mn, w, q, out);
}

// Round 18
// 255.685 us; speedup vs baseline: 1.2326x; 1.2326x over previous
//
#include <hip/hip_runtime.h>

#define B_  128
#define LC_ 512
#define LM_ 512
#define D_  512

typedef __attribute__((ext_vector_type(8))) short short8;
typedef __attribute__((ext_vector_type(16))) float f32x16;
typedef unsigned int u32;

__device__ __forceinline__ unsigned short bf16_rn(float x) {
  unsigned u = __float_as_uint(x);
  unsigned r = u + 0x7fffu + ((u >> 16) & 1u);
  return (unsigned short)(r >> 16);
}
__device__ __forceinline__ float bf2f(short s) {
  return __uint_as_float((u32)(unsigned short)s << 16);
}
__device__ __forceinline__ void gl_lds16(const void* g, void* l) {
  __builtin_amdgcn_global_load_lds((const __attribute__((address_space(1))) u32*)g,
                                   (__attribute__((address_space(3))) u32*)l, 16, 0, 0);
}

// one fp32 -> (hi,lo) bf16 split + u-dot accumulate; constant IDX only
#define CVT1(SRC, WS, AH, AL, IDX, ACCU)                         \
  { unsigned short hb_ = bf16_rn(SRC);                           \
    float hf_ = __uint_as_float((u32)hb_ << 16);                 \
    AH[IDX] = (short)hb_;                                        \
    AL[IDX] = (short)bf16_rn((SRC) - hf_);                       \
    ACCU = fmaf((SRC), (WS), ACCU); }

// ---------------- k_cvt_main: main fp32 -> tiled fragment-order bf16 planes
// Bt[b][ks][mt][lane][8]; also fused v = main·W. Wave = one (b, mt) tile.
__global__ __launch_bounds__(256) void k_cvt_main(
    const float* __restrict__ mn, const float* __restrict__ W,
    short* __restrict__ BtH, short* __restrict__ BtL,
    float* __restrict__ v) {
  __shared__ float sW[512];
  int tid = threadIdx.x;
  sW[tid] = W[tid];
  sW[tid + 256] = W[tid + 256];
  __syncthreads();
  int wave = blockIdx.x * 4 + (tid >> 6);
  int b = wave >> 4, mt = wave & 15;
  int lane = tid & 63, rowl = lane & 31, h = lane >> 5;
  const float* src = mn + ((size_t)b * LM_ + 32 * mt + rowl) * D_ + 8 * h;
  float acc = 0.f;
  for (int ks = 0; ks < 32; ks++) {
    float4 f0 = *(const float4*)(src + 16 * ks);
    float4 f1 = *(const float4*)(src + 16 * ks + 4);
    int k = 16 * ks + 8 * h;
    float4 w0 = *(const float4*)&sW[k];
    float4 w1 = *(const float4*)&sW[k + 4];
    short8 vh, vl;
    CVT1(f0.x, w0.x, vh, vl, 0, acc); CVT1(f0.y, w0.y, vh, vl, 1, acc);
    CVT1(f0.z, w0.z, vh, vl, 2, acc); CVT1(f0.w, w0.w, vh, vl, 3, acc);
    CVT1(f1.x, w1.x, vh, vl, 4, acc); CVT1(f1.y, w1.y, vh, vl, 5, acc);
    CVT1(f1.z, w1.z, vh, vl, 6, acc); CVT1(f1.w, w1.w, vh, vl, 7, acc);
    size_t off = (((size_t)b * 32 + ks) * 16 + mt) * 512 + (size_t)lane * 8;
    *(short8*)(BtH + off) = vh;
    *(short8*)(BtL + off) = vl;
  }
  acc += __shfl_xor(acc, 32, 64);
  if (h == 0) v[b * LM_ + 32 * mt + rowl] = acc;
}

// ---------------- K1: exact R7 k_scores_mfma3 (proven 152 us), with the ONE
// change: P stored as bf16 (t-partials still computed from fp32 in-register).
struct __align__(16) Smem3 {
  short8 Bf[2][2][16][64];   // [buf][pl][mt][lane]  64 KB
  short8 Af[2][2][4][64];    // [buf][pl][rt][lane]  16 KB
  float sW[512];
  float red[4][128];
  float cmb[128];
  float uld[128];
  float tpw[2][4][128];
};

__global__ __launch_bounds__(512, 2) void k_scores_mfma9(
    const float* __restrict__ ctx, const short* __restrict__ BtH,
    const short* __restrict__ BtL, const float* __restrict__ W,
    unsigned short* __restrict__ P16, float* __restrict__ tpart) {
  __shared__ Smem3 sm;
  int p = blockIdx.x;
  int b = (p & 7) | ((p >> 5) << 3);   // 4 c-blocks of a batch -> same XCD
  int cblk = (p >> 3) & 3;
  int c0 = cblk * 128;
  int tid = threadIdx.x;
  int lane = tid & 63, wv = tid >> 6;
  int rowl = lane & 31, h = lane >> 5;

  f32x16 acc[2][4];
  #pragma unroll
  for (int r = 0; r < 2; r++)
    #pragma unroll
    for (int mtl = 0; mtl < 4; mtl++)
      #pragma unroll
      for (int j = 0; j < 16; j++) acc[r][mtl][j] = 0.f;

  auto stageB = [&](int bf, int ks) {
    #pragma unroll
    for (int rep = 0; rep < 2; rep++) {
      int mt = wv + 8 * rep;
      size_t off = (((size_t)b * 32 + ks) * 16 + mt) * 512 + (size_t)lane * 8;
      gl_lds16(BtH + off, &sm.Bf[bf][0][mt][0]);
      gl_lds16(BtL + off, &sm.Bf[bf][1][mt][0]);
    }
  };
  auto cvtA = [&](int bf, int ks, const float4& g0, const float4& g1, float& au) {
    float xs[8] = {g0.x, g0.y, g0.z, g0.w, g1.x, g1.y, g1.z, g1.w};
    int k = 16 * ks + 8 * h;
    float4 w0 = *(const float4*)&sm.sW[k];
    float4 w1 = *(const float4*)&sm.sW[k + 4];
    float ws[8] = {w0.x, w0.y, w0.z, w0.w, w1.x, w1.y, w1.z, w1.w};
    short8 vh, vl;
    #pragma unroll
    for (int e = 0; e < 8; e++) {
      unsigned short hb = bf16_rn(xs[e]);
      float hf = __uint_as_float((unsigned)hb << 16);
      vh[e] = (short)hb;
      vl[e] = (short)bf16_rn(xs[e] - hf);
      au = fmaf(xs[e], ws[e], au);
    }
    *(short8*)&sm.Af[bf][0][wv][lane] = vh;
    *(short8*)&sm.Af[bf][1][wv][lane] = vl;
  };

  sm.sW[tid] = W[tid];
  float accu = 0.f;
  stageB(0, 0);
  const float* arow = ctx + ((size_t)b * LC_ + c0 + 32 * wv + rowl) * D_ + 8 * h;
  float4 g0, g1;
  if (wv < 4) {
    g0 = *(const float4*)(arow);
    g1 = *(const float4*)(arow + 4);
  }
  __syncthreads();                      // sW visible
  if (wv < 4) cvtA(0, 0, g0, g1, accu);
  __syncthreads();                      // Af written, Bf gl_lds drained

  for (int ks = 0; ks < 32; ks++) {
    int buf = ks & 1;
    if (ks < 31) {
      stageB(buf ^ 1, ks + 1);
      if (wv < 4) {
        const float* ap = arow + 16 * (ks + 1);
        g0 = *(const float4*)ap;
        g1 = *(const float4*)(ap + 4);
      }
    }
    int rt0 = (wv >> 2) * 2;
    short8 ah0 = sm.Af[buf][0][rt0][lane];
    short8 ah1 = sm.Af[buf][0][rt0 + 1][lane];
    short8 al0 = sm.Af[buf][1][rt0][lane];
    short8 al1 = sm.Af[buf][1][rt0 + 1][lane];
    #pragma unroll
    for (int mtl = 0; mtl < 4; mtl++) {
      int mtg = (wv & 3) * 4 + mtl;
      short8 bh = sm.Bf[buf][0][mtg][lane];
      short8 bl = sm.Bf[buf][1][mtg][lane];
      acc[0][mtl] = __builtin_amdgcn_mfma_f32_32x32x16_bf16(ah0, bh, acc[0][mtl], 0, 0, 0);
      acc[0][mtl] = __builtin_amdgcn_mfma_f32_32x32x16_bf16(ah0, bl, acc[0][mtl], 0, 0, 0);
      acc[0][mtl] = __builtin_amdgcn_mfma_f32_32x32x16_bf16(al0, bh, acc[0][mtl], 0, 0, 0);
      acc[1][mtl] = __builtin_amdgcn_mfma_f32_32x32x16_bf16(ah1, bh, acc[1][mtl], 0, 0, 0);
      acc[1][mtl] = __builtin_amdgcn_mfma_f32_32x32x16_bf16(ah1, bl, acc[1][mtl], 0, 0, 0);
      acc[1][mtl] = __builtin_amdgcn_mfma_f32_32x32x16_bf16(al1, bh, acc[1][mtl], 0, 0, 0);
    }
    if (ks < 31 && wv < 4) cvtA(buf ^ 1, ks + 1, g0, g1, accu);
    __syncthreads();
  }

  // u for this block's 128 c-rows (stage waves computed the dot)
  if (wv < 4) {
    accu += __shfl_xor(accu, 32, 64);
    if (h == 0) sm.uld[32 * wv + rowl] = accu;
  }

  // ---- softmax over m=512 per c-row (cross-wave via LDS) ----
  #pragma unroll
  for (int r = 0; r < 2; r++)
    #pragma unroll
    for (int j = 0; j < 16; j++) {
      float mx = fmaxf(fmaxf(acc[r][0][j], acc[r][1][j]),
                       fmaxf(acc[r][2][j], acc[r][3][j]));
      #pragma unroll
      for (int s = 1; s <= 16; s <<= 1) mx = fmaxf(mx, __shfl_xor(mx, s, 64));
      if (rowl == 0)
        sm.red[wv & 3][64 * (wv >> 2) + 32 * r + (j & 3) + 8 * (j >> 2) + 4 * h] = mx;
    }
  __syncthreads();
  if (tid < 128)
    sm.cmb[tid] = fmaxf(fmaxf(sm.red[0][tid], sm.red[1][tid]),
                        fmaxf(sm.red[2][tid], sm.red[3][tid]));
  __syncthreads();
  #pragma unroll
  for (int r = 0; r < 2; r++)
    #pragma unroll
    for (int j = 0; j < 16; j++) {
      int row = 64 * (wv >> 2) + 32 * r + (j & 3) + 8 * (j >> 2) + 4 * h;
      float mx = sm.cmb[row];
      float s = 0.f;
      #pragma unroll
      for (int mtl = 0; mtl < 4; mtl++) {
        float e = __expf(acc[r][mtl][j] - mx);
        acc[r][mtl][j] = e;
        s += e;
      }
      #pragma unroll
      for (int st = 1; st <= 16; st <<= 1) s += __shfl_xor(s, st, 64);
      if (rowl == 0) sm.red[wv & 3][row] = s;
    }
  __syncthreads();
  if (tid < 128)
    sm.cmb[tid] = sm.red[0][tid] + sm.red[1][tid] + sm.red[2][tid] + sm.red[3][tid];
  __syncthreads();

  // ---- P write (bf16) + fused t-partials (fp32) ----
  unsigned short* Pb = P16 + ((size_t)b * LC_ + c0) * LM_;
  float tp[4] = {0.f, 0.f, 0.f, 0.f};
  #pragma unroll
  for (int r = 0; r < 2; r++)
    #pragma unroll
    for (int j = 0; j < 16; j++) {
      int row = 64 * (wv >> 2) + 32 * r + (j & 3) + 8 * (j >> 2) + 4 * h;
      float rinv = 1.f / sm.cmb[row];
      float uu = sm.uld[row];
      #pragma unroll
      for (int mtl = 0; mtl < 4; mtl++) {
        float pv = acc[r][mtl][j] * rinv;
        Pb[(size_t)row * LM_ + 128 * (wv & 3) + 32 * mtl + rowl] = bf16_rn(pv);
        tp[mtl] = fmaf(pv, uu, tp[mtl]);
      }
    }
  #pragma unroll
  for (int mtl = 0; mtl < 4; mtl++) tp[mtl] += __shfl_xor(tp[mtl], 32, 64);
  if (h == 0) {
    #pragma unroll
    for (int mtl = 0; mtl < 4; mtl++)
      sm.tpw[wv >> 2][wv & 3][32 * mtl + rowl] = tp[mtl];
  }
  __syncthreads();
  {
    int m = tid;
    tpart[((size_t)b * 4 + cblk) * LM_ + m] =
        sm.tpw[0][m >> 7][m & 127] + sm.tpw[1][m >> 7][m & 127];
  }
}

// ---------------- k_tw: t = v - sum(tpart, 4); w = softmax(t) --------------
__global__ __launch_bounds__(256) void k_tw(const float* __restrict__ tpart,
                                            const float* __restrict__ v,
                                            float* __restrict__ w_) {
  int b = blockIdx.x;
  int tid = threadIdx.x;
  int m0 = tid * 2;
  const float* tp = tpart + (size_t)b * 4 * LM_;
  float s0 = 0.f, s1 = 0.f;
  #pragma unroll
  for (int cb = 0; cb < 4; cb++) {
    s0 += tp[cb * LM_ + m0];
    s1 += tp[cb * LM_ + m0 + 1];
  }
  float x0 = v[b * LM_ + m0] - s0;
  float x1 = v[b * LM_ + m0 + 1] - s1;
  float mx = fmaxf(x0, x1);
  #pragma unroll
  for (int s = 32; s >= 1; s >>= 1) mx = fmaxf(mx, __shfl_xor(mx, s, 64));
  __shared__ float redm[4], reds[4];
  int wvv = tid >> 6, ln = tid & 63;
  if (ln == 0) redm[wvv] = mx;
  __syncthreads();
  mx = fmaxf(fmaxf(redm[0], redm[1]), fmaxf(redm[2], redm[3]));
  float e0 = __expf(x0 - mx), e1 = __expf(x1 - mx);
  float sum = e0 + e1;
  #pragma unroll
  for (int s = 32; s >= 1; s >>= 1) sum += __shfl_xor(sum, s, 64);
  if (ln == 0) reds[wvv] = sum;
  __syncthreads();
  sum = reds[0] + reds[1] + reds[2] + reds[3];
  float rinv = 1.0f / sum;
  float2 o; o.x = e0 * rinv; o.y = e1 * rinv;
  *(float2*)&w_[b * LM_ + m0] = o;
}

// ---------------- k_q: q[b,c] = sum_m bf16(P)[b,c,m]*w[b,m] ----------------
__global__ __launch_bounds__(256) void k_q(const unsigned short* __restrict__ P16,
                                           const float* __restrict__ w,
                                           float* __restrict__ q) {
  int b = blockIdx.y;
  int c0 = blockIdx.x * 32;
  int wvv = threadIdx.x >> 6, ln = threadIdx.x & 63;
  __shared__ float sw[LM_];
  *(float2*)&sw[threadIdx.x * 2] = *(const float2*)&w[b * LM_ + threadIdx.x * 2];
  __syncthreads();
  #pragma unroll
  for (int rr = 0; rr < 8; rr++) {
    int c = c0 + wvv * 8 + rr;
    short8 pv = *((const short8*)(P16 + ((size_t)b * LC_ + c) * LM_) + ln);
    float4 w0 = *(const float4*)&sw[ln * 8];
    float4 w1 = *(const float4*)&sw[ln * 8 + 4];
    float acc = bf2f(pv[0]) * w0.x + bf2f(pv[1]) * w0.y
              + bf2f(pv[2]) * w0.z + bf2f(pv[3]) * w0.w
              + bf2f(pv[4]) * w1.x + bf2f(pv[5]) * w1.y
              + bf2f(pv[6]) * w1.z + bf2f(pv[7]) * w1.w;
    #pragma unroll
    for (int s = 32; s >= 1; s >>= 1) acc += __shfl_xor(acc, s, 64);
    if (ln == 0) q[b * LC_ + c] = acc;
  }
}

// ---------------- k_out: out[b,d] = sum_m w*main(planes) - sum_c q*ctx -----
// main-part reads the bf16 hi/lo planes (exact to 2^-17), ctx-part fp32.
__global__ __launch_bounds__(256) void k_out(const float* __restrict__ ctx,
                                             const short* __restrict__ BtH,
                                             const short* __restrict__ BtL,
                                             const float* __restrict__ w,
                                             const float* __restrict__ q,
                                             float* __restrict__ out) {
  int b = blockIdx.y;
  int d0 = blockIdx.x * 64;
  int ks0 = d0 >> 4;                 // 4 ks-slices cover this 64-wide d block
  int tid = threadIdx.x;
  int lane = tid & 63, wvv = tid >> 6;
  int rowl = lane & 31, h = lane >> 5;
  __shared__ float sw_[LM_];
  __shared__ float redo[4][64];
  __shared__ float red2[4][64];
  sw_[tid] = w[b * LM_ + tid];
  sw_[tid + 256] = w[b * LM_ + tid + 256];
  __syncthreads();

  // ---- main part from planes: wave wvv handles mt = wvv, wvv+4, ... ----
  float mp[4][8];
  #pragma unroll
  for (int ksl = 0; ksl < 4; ksl++)
    #pragma unroll
    for (int e = 0; e < 8; e++) mp[ksl][e] = 0.f;
  for (int mt = wvv; mt < 16; mt += 4) {
    float wm = sw_[32 * mt + rowl];
    #pragma unroll
    for (int ksl = 0; ksl < 4; ksl++) {
      size_t off = (((size_t)b * 32 + ks0 + ksl) * 16 + mt) * 512 + (size_t)lane * 8;
      short8 hh = *(const short8*)(BtH + off);
      short8 ll = *(const short8*)(BtL + off);
      #pragma unroll
      for (int e = 0; e < 8; e++)
        mp[ksl][e] = fmaf(wm, bf2f(hh[e]) + bf2f(ll[e]), mp[ksl][e]);
    }
  }
  // reduce over the 32 rowl lanes (xor steps stay within each h-half)
  #pragma unroll
  for (int ksl = 0; ksl < 4; ksl++)
    #pragma unroll
    for (int e = 0; e < 8; e++) {
      float vsum = mp[ksl][e];
      #pragma unroll
      for (int s = 1; s <= 16; s <<= 1) vsum += __shfl_xor(vsum, s, 64);
      mp[ksl][e] = vsum;
    }
  if (rowl == 0) {
    #pragma unroll
    for (int ksl = 0; ksl < 4; ksl++)
      #pragma unroll
      for (int e = 0; e < 8; e++)
        redo[wvv][16 * ksl + 8 * h + e] = mp[ksl][e];
  }

  // ---- ctx part (fp32, as before) ----
  int td = tid & 63;
  int tg = tid >> 6;
  const float* Cb = ctx + (size_t)b * LC_ * D_ + d0;
  const float* qb = q + b * LC_;
  float acc = 0.f;
  #pragma unroll 4
  for (int c = tg; c < LC_; c += 4) acc -= qb[c] * Cb[(size_t)c * D_ + td];
  red2[tg][td] = acc;
  __syncthreads();
  if (tg == 0)
    out[b * D_ + d0 + td] =
        redo[0][td] + redo[1][td] + redo[2][td] + redo[3][td] +
        red2[0][td] + red2[1][td] + red2[2][td] + red2[3][td];
}

// =====================  LAUNCH  ============================================
extern "C" void kernel_launch(void* const* d_in, const int* in_sizes, int n_in,
                              void* d_out, int out_size, void* d_ws, size_t ws_size,
                              hipStream_t stream) {
  const float* ctx = (const float*)d_in[0];
  const float* mn  = (const float*)d_in[1];
  const float* W   = (const float*)d_in[2];
  float* out = (float*)d_out;

  char* base = (char*)d_ws;
  size_t nP16   = (size_t)B_ * LC_ * LM_ * 2;        // 67 MB (bf16 P)
  size_t planeB = (size_t)B_ * LM_ * D_ * 2;         // 67 MB per plane

  unsigned short* P16 = (unsigned short*)base;
  short* BtH = (short*)(base + nP16);
  short* BtL = (short*)(base + nP16 + planeB);
  char* p2 = base + nP16 + 2 * planeB;
  float* tpart = (float*)p2;  p2 += (size_t)B_ * 4 * LM_ * 4;
  float* v = (float*)p2;      p2 += (size_t)B_ * LM_ * 4;
  float* w = (float*)p2;      p2 += (size_t)B_ * LM_ * 4;
  float* q = (float*)p2;

  k_cvt_main<<<dim3(512), 256, 0, stream>>>(mn, W, BtH, BtL, v);
  k_scores_mfma9<<<dim3(512), 512, 0, stream>>>(ctx, BtH, BtL, W, P16, tpart);
  k_tw<<<dim3(B_), 256, 0, stream>>>(tpart, v, w);
  k_q<<<dim3(LC_ / 32, B_), 256, 0, stream>>>(P16, w, q);
  k_out<<<dim3(D_ / 64, B_), 256, 0, stream>>>(ctx, BtH, BtL, w, q, out);
}